// Round 4
// baseline (25249.867 us; speedup 1.0000x reference)
//
#include <hip/hip_runtime.h>

// TimeVAEDecoder: B=128, LAT=128, H=512, F=128, L=256, NL=2
// Round 4: same verified numerics as round 3 (3-plane bf16 split, 6 MFMA
// products, two-pass LN), restructured for occupancy + weight reuse:
//  - cell_k: 128 blocks x 1024 thr (16 waves = 4/SIMD), tile M=32 x (16h x 4g),
//    waves = gate x Mtile x Khalf, LDS reduce; accum split 4-way (dep chain <= 2)
//  - lnpre_k: 256 blocks (full GPU), register-held LN stats
//  - gbuf padded [16][17] vs 4-way LDS bank conflict

typedef unsigned int uint32;
typedef unsigned short u16;
typedef __attribute__((ext_vector_type(8))) short bf16x8;
typedef __attribute__((ext_vector_type(4))) float f32x4;

static constexpr int Ln = 256, Fn = 128;
static constexpr int APS = 65536;    // activation plane stride (elems): 128x512
static constexpr int WPS = 2097152;  // cell-weight plane stride: 2048x1024
static constexpr int OPS = 65536;    // W_out plane stride: 128x512
static constexpr int PPS = 262144;   // W_pre plane stride: 512x512

__device__ __forceinline__ u16 f2bf(float f) {
  union { float f; uint32 u; } v; v.f = f;
  uint32 u = v.u + 0x7fffu + ((v.u >> 16) & 1u);
  return (u16)(u >> 16);
}
__device__ __forceinline__ float bf2f(u16 h) {
  union { uint32 u; float f; } v; v.u = ((uint32)h) << 16;
  return v.f;
}
// 3-plane split: v = hi + mid + lo + O(2^-24 |v|)
__device__ __forceinline__ void splitbf3(float v, u16* hi, u16* mid, u16* lo) {
  u16 h = f2bf(v);
  float r = v - bf2f(h);
  u16 m = f2bf(r);
  float r2 = r - bf2f(m);
  *hi = h; *mid = m; *lo = f2bf(r2);
}
__device__ __forceinline__ float sigm(float x) { return 1.f / (1.f + expf(-x)); }
__device__ __forceinline__ bf16x8 ldf(const u16* p) { return *(const bf16x8*)p; }

#define MFMA1(A, B, ACC) ACC = __builtin_amdgcn_mfma_f32_16x16x32_bf16((A), (B), (ACC), 0, 0, 0)
// 6 products, 4 accumulators (max dependent chain per iter = 2):
// A0 += hh ; A1 += hm+mh ; A2 += hl+mm ; A3 += lh
#define MFMA6(AH, AM, AL, BH, BM, BL, A0, A1, A2, A3) \
  do {                                                \
    MFMA1(AH, BH, A0);                                \
    MFMA1(AH, BM, A1); MFMA1(AM, BH, A1);             \
    MFMA1(AH, BL, A2); MFMA1(AM, BM, A2);             \
    MFMA1(AL, BH, A3);                                \
  } while (0)

// ---------------- prep kernels (unchanged from round 3) ----------------

__global__ void prep_hc0(const float* __restrict__ z,
                         const float* __restrict__ W_l2h, const float* __restrict__ b_l2h,
                         const float* __restrict__ W_l2c, const float* __restrict__ b_l2c,
                         u16* __restrict__ ha0, u16* __restrict__ hb0,
                         float* __restrict__ ca, float* __restrict__ cb) {
  int idx = blockIdx.x * 256 + threadIdx.x;  // 131072
  int b = idx & 127, j = idx >> 7;
  float ah = b_l2h[j], ac = b_l2c[j];
  for (int k = 0; k < 128; ++k) {
    float zv = z[b * 128 + k];
    ah += zv * W_l2h[j * 128 + k];
    ac += zv * W_l2c[j * 128 + k];
  }
  int flat = b * 1024 + j;
  if (flat < 65536) {
    splitbf3(ah, &ha0[flat], &ha0[APS + flat], &ha0[2 * APS + flat]);
    ca[flat] = ac;
  } else {
    flat -= 65536;
    splitbf3(ah, &hb0[flat], &hb0[APS + flat], &hb0[2 * APS + flat]);
    cb[flat] = ac;
  }
}

__global__ void prep_zp(const float* __restrict__ z, const float* __restrict__ W_zp,
                        const float* __restrict__ b_zp, float* __restrict__ zp) {
  int idx = blockIdx.x * 256 + threadIdx.x;  // 65536
  int b = idx & 127, h = idx >> 7;
  float a = b_zp[h];
  for (int k = 0; k < 128; ++k) a += z[b * 128 + k] * W_zp[h * 128 + k];
  zp[b * 512 + h] = a;
}

__global__ void prep_gz(const float* __restrict__ zp, const float* __restrict__ W_ih0,
                        const float* __restrict__ b_ih0, const float* __restrict__ b_hh0,
                        const float* __restrict__ b_out,
                        float* __restrict__ GZ0, float* __restrict__ GZ1) {
  int idx = blockIdx.x * 256 + threadIdx.x;  // 262144
  int b = idx & 127, g = idx >> 7;
  const float* wr = W_ih0 + (size_t)g * 640;
  float a = b_ih0[g] + b_hh0[g];
  for (int k = 0; k < 512; ++k) a += zp[b * 512 + k] * wr[128 + k];
  float co = 0.f;
  for (int f = 0; f < 128; ++f) co += b_out[f] * wr[f];
  GZ0[b * 2048 + g] = a;
  GZ1[b * 2048 + g] = a + co;
}

__global__ void prep_waf(const float* __restrict__ W_out, const float* __restrict__ W_ih0,
                         const float* __restrict__ W_hh0, u16* __restrict__ WAf) {
  int idx = blockIdx.x * 256 + threadIdx.x;  // 2097152
  int k = idx & 1023, g = idx >> 10;
  float v;
  if (k < 512) {
    v = 0.f;
    const float* wr = W_ih0 + (size_t)g * 640;
    for (int f = 0; f < 128; ++f) v += W_out[f * 512 + k] * wr[f];
  } else {
    v = W_hh0[(size_t)g * 512 + (k - 512)];
  }
  splitbf3(v, &WAf[idx], &WAf[WPS + idx], &WAf[2 * WPS + idx]);
}

__global__ void prep_wbf(const float* __restrict__ W_ih1, const float* __restrict__ W_hh1,
                         u16* __restrict__ WBf) {
  int idx = blockIdx.x * 256 + threadIdx.x;  // 2097152
  int k = idx & 1023, g = idx >> 10;
  float v = (k < 512) ? W_ih1[(size_t)g * 512 + k] : W_hh1[(size_t)g * 512 + (k - 512)];
  splitbf3(v, &WBf[idx], &WBf[WPS + idx], &WBf[2 * WPS + idx]);
}

__global__ void prep_misc(const float* __restrict__ W_pre, const float* __restrict__ W_out,
                          const float* __restrict__ b_ih1, const float* __restrict__ b_hh1,
                          u16* __restrict__ WPf, u16* __restrict__ WOf,
                          float* __restrict__ gb1, u16* __restrict__ s) {
  int idx = blockIdx.x * 256 + threadIdx.x;  // 526336 total
  if (idx < 262144) { splitbf3(W_pre[idx], &WPf[idx], &WPf[PPS + idx], &WPf[2 * PPS + idx]); return; }
  idx -= 262144;
  if (idx < 65536) { splitbf3(W_out[idx], &WOf[idx], &WOf[OPS + idx], &WOf[2 * OPS + idx]); return; }
  idx -= 65536;
  if (idx < 2048) { gb1[idx] = b_ih1[idx] + b_hh1[idx]; return; }
  idx -= 2048;
  if (idx < 196608) s[idx] = 0;  // all 3 planes of s
}

// ---------------- per-step kernels ----------------

// LSTM cell. Gate blocks (blk < n_gate_blocks = 128): tile M=32, 16 h-cols x 4 gates.
// 16 waves: gate = w&3, mt = (w>>2)&1, kh = w>>3 (K-half selects x0/x1).
// ys blocks (phase A, 8 blocks): ys[t-1] = s @ W_out^T + b_out, N=16 f-slice,
// waves = Mtile(8) x Khalf(2).
__global__ __launch_bounds__(1024, 4) void cell_k(
    const u16* __restrict__ x0, const u16* __restrict__ x1,
    const u16* __restrict__ Wf,
    const float* __restrict__ bias, int bias_stride,
    float* __restrict__ cstate, u16* __restrict__ hout,
    int n_gate_blocks,
    const u16* sv, const u16* __restrict__ WOf,
    const float* __restrict__ b_out, float* __restrict__ ys, int t) {
  int tid = threadIdx.x;
  int lane = tid & 63, w = tid >> 6;
  int q = lane >> 4, r16 = lane & 15;
  __shared__ float gbuf[16][16][17];
  int blk = blockIdx.x;
  if (blk < n_gate_blocks) {
    int hg = blk & 31, mg = blk >> 5;  // hg fast -> XCD-local weight slices
    int gate = w & 3, mt = (w >> 2) & 1, kh = w >> 3;
    const u16* xs = kh ? x1 : x0;
    const u16* wr = Wf + (size_t)(gate * 512 + hg * 16 + r16) * 1024 + kh * 512 + q * 8;
    const u16* ar = xs + (size_t)(mg * 32 + mt * 16 + r16) * 512 + q * 8;
    f32x4 A0 = {0.f, 0.f, 0.f, 0.f}, A1 = A0, A2 = A0, A3 = A0;
#pragma unroll 8
    for (int kb = 0; kb < 16; ++kb) {
      bf16x8 ah = ldf(ar + kb * 32), am = ldf(ar + APS + kb * 32), al = ldf(ar + 2 * APS + kb * 32);
      bf16x8 bh = ldf(wr + kb * 32), bm = ldf(wr + WPS + kb * 32), bl = ldf(wr + 2 * WPS + kb * 32);
      MFMA6(ah, am, al, bh, bm, bl, A0, A1, A2, A3);
    }
#pragma unroll
    for (int r = 0; r < 4; ++r)
      gbuf[w][q * 4 + r][r16] = ((A3[r] + A2[r]) + A1[r]) + A0[r];
    __syncthreads();
    if (tid < 512) {
      int bl_ = tid >> 4, hl = tid & 15;       // bl_ in [0,32)
      int mt2 = bl_ >> 4, brow = bl_ & 15;
      int b = mg * 32 + bl_, h = hg * 16 + hl;
      float g4[4];
#pragma unroll
      for (int g = 0; g < 4; ++g) {
        int w0 = g | (mt2 << 2);
        g4[g] = gbuf[w0][brow][hl] + gbuf[w0 + 8][brow][hl];
      }
      const float* bb = bias + (size_t)b * bias_stride;  // 2048 (GZ) or 0 (gb1)
      float gi = g4[0] + bb[h];
      float gf = g4[1] + bb[512 + h];
      float gc = g4[2] + bb[1024 + h];
      float go = g4[3] + bb[1536 + h];
      int idx = b * 512 + h;
      float c = cstate[idx];
      float cn = sigm(gf) * c + sigm(gi) * tanhf(gc);
      cstate[idx] = cn;
      float hv = sigm(go) * tanhf(cn);
      splitbf3(hv, &hout[idx], &hout[APS + idx], &hout[2 * APS + idx]);
    }
  } else {
    if (t < 1) return;  // uniform per block: safe
    int ob = blk - n_gate_blocks;  // [0,8): f-slice
    int f0 = ob * 16;
    int mt8 = w & 7, kh = w >> 3;  // K=256 halves
    const u16* wr = WOf + (size_t)(f0 + r16) * 512 + kh * 256 + q * 8;
    const u16* ar = sv + (size_t)(mt8 * 16 + r16) * 512 + kh * 256 + q * 8;
    f32x4 A0 = {0.f, 0.f, 0.f, 0.f}, A1 = A0, A2 = A0, A3 = A0;
#pragma unroll
    for (int kb = 0; kb < 8; ++kb) {
      bf16x8 ah = ldf(ar + kb * 32), am = ldf(ar + APS + kb * 32), al = ldf(ar + 2 * APS + kb * 32);
      bf16x8 bh = ldf(wr + kb * 32), bm = ldf(wr + OPS + kb * 32), bl = ldf(wr + 2 * OPS + kb * 32);
      MFMA6(ah, am, al, bh, bm, bl, A0, A1, A2, A3);
    }
#pragma unroll
    for (int r = 0; r < 4; ++r)
      gbuf[w][q * 4 + r][r16] = ((A3[r] + A2[r]) + A1[r]) + A0[r];
    __syncthreads();
    int fl = tid & 15, bh2 = tid >> 4;  // bh2 in [0,64)
    float bo = b_out[f0 + fl];
#pragma unroll
    for (int i = 0; i < 2; ++i) {
      int b = bh2 + i * 64;
      int w0 = b >> 4;
      float val = gbuf[w0][b & 15][fl] + gbuf[w0 + 8][b & 15][fl] + bo;
      ys[(size_t)b * (Ln * Fn) + (size_t)(t - 1) * Fn + f0 + fl] = val;
    }
  }
}

// LN(hb) -> pre = relu(ln@W_pre^T + b_pre) -> s = pre + ln
// 256 blocks (bg 8 x jg 32, jg fast); 256 thr; LN stats in registers (two-pass).
__global__ __launch_bounds__(256, 2) void lnpre_k(
    const u16* __restrict__ hb, const u16* __restrict__ WPf,
    const float* __restrict__ lng, const float* __restrict__ lnb,
    const float* __restrict__ b_pre, u16* __restrict__ s_out) {
  int tid = threadIdx.x;
  int lane = tid & 63, w = tid >> 6;
  int q = lane >> 4, r16 = lane & 15;
  int jg = blockIdx.x & 31, bg = blockIdx.x >> 5;
  int j0 = jg * 16, b0 = bg * 16;
  __shared__ u16 lnH[16 * 520], lnM[16 * 520], lnL[16 * 520];
  __shared__ float red[16][16], smean[16], srstd[16];
  __shared__ float gbuf[4][16][17];
  int rl = tid >> 4, cg = tid & 15;
  float v[32];
  {
    const u16* hr = hb + (size_t)(b0 + rl) * 512 + cg * 32;
    float sm = 0.f;
#pragma unroll
    for (int kk = 0; kk < 32; ++kk) {
      v[kk] = (bf2f(hr[2 * APS + kk]) + bf2f(hr[APS + kk])) + bf2f(hr[kk]);
      sm += v[kk];
    }
    red[rl][cg] = sm;
  }
  __syncthreads();
  if (tid < 16) {
    float s1 = 0.f;
    for (int i = 0; i < 16; ++i) s1 += red[tid][i];
    smean[tid] = s1 * (1.f / 512.f);
  }
  __syncthreads();
  float m = smean[rl];
  {
    float sq = 0.f;
#pragma unroll
    for (int kk = 0; kk < 32; ++kk) { float d = v[kk] - m; sq += d * d; }
    red[rl][cg] = sq;
  }
  __syncthreads();
  if (tid < 16) {
    float s2 = 0.f;
    for (int i = 0; i < 16; ++i) s2 += red[tid][i];
    srstd[tid] = 1.f / sqrtf(s2 * (1.f / 512.f) + 1e-5f);
  }
  __syncthreads();
  float rs = srstd[rl];
#pragma unroll
  for (int kk = 0; kk < 32; ++kk) {
    int col = cg * 32 + kk;
    float lv = (v[kk] - m) * rs * lng[col] + lnb[col];
    splitbf3(lv, &lnH[rl * 520 + col], &lnM[rl * 520 + col], &lnL[rl * 520 + col]);
  }
  __syncthreads();
  // GEMM: N=16 (j0 slice), K=512 quartered across 4 waves (kb in [4w, 4w+4))
  const u16* wr = WPf + (size_t)(j0 + r16) * 512 + w * 128 + q * 8;
  const u16* aH = lnH + r16 * 520 + w * 128 + q * 8;
  const u16* aM = lnM + r16 * 520 + w * 128 + q * 8;
  const u16* aL = lnL + r16 * 520 + w * 128 + q * 8;
  f32x4 A0 = {0.f, 0.f, 0.f, 0.f}, A1 = A0, A2 = A0, A3 = A0;
#pragma unroll
  for (int kb = 0; kb < 4; ++kb) {
    bf16x8 ah = ldf(aH + kb * 32), am = ldf(aM + kb * 32), al = ldf(aL + kb * 32);
    bf16x8 bh = ldf(wr + kb * 32), bm = ldf(wr + PPS + kb * 32), bl = ldf(wr + 2 * PPS + kb * 32);
    MFMA6(ah, am, al, bh, bm, bl, A0, A1, A2, A3);
  }
#pragma unroll
  for (int r = 0; r < 4; ++r)
    gbuf[w][q * 4 + r][r16] = ((A3[r] + A2[r]) + A1[r]) + A0[r];
  __syncthreads();
  int bl_ = tid >> 4, jl = tid & 15;
  int col = j0 + jl;
  float pre = ((gbuf[3][bl_][jl] + gbuf[2][bl_][jl]) + gbuf[1][bl_][jl]) + gbuf[0][bl_][jl]
              + b_pre[col];
  pre = fmaxf(pre, 0.f);
  float lnv = (bf2f(lnL[bl_ * 520 + col]) + bf2f(lnM[bl_ * 520 + col])) + bf2f(lnH[bl_ * 520 + col]);
  float sval = pre + lnv;
  size_t sidx = (size_t)(b0 + bl_) * 512 + col;
  splitbf3(sval, &s_out[sidx], &s_out[APS + sidx], &s_out[2 * APS + sidx]);
}

// ---------------- host ----------------

extern "C" void kernel_launch(void* const* d_in, const int* in_sizes, int n_in,
                              void* d_out, int out_size, void* d_ws, size_t ws_size,
                              hipStream_t stream) {
  const float* z     = (const float*)d_in[0];
  const float* W_l2h = (const float*)d_in[1];
  const float* b_l2h = (const float*)d_in[2];
  const float* W_l2c = (const float*)d_in[3];
  const float* b_l2c = (const float*)d_in[4];
  const float* W_zp  = (const float*)d_in[5];
  const float* b_zp  = (const float*)d_in[6];
  const float* W_ih0 = (const float*)d_in[7];
  const float* W_hh0 = (const float*)d_in[8];
  const float* b_ih0 = (const float*)d_in[9];
  const float* b_hh0 = (const float*)d_in[10];
  const float* W_ih1 = (const float*)d_in[11];
  const float* W_hh1 = (const float*)d_in[12];
  const float* b_ih1 = (const float*)d_in[13];
  const float* b_hh1 = (const float*)d_in[14];
  const float* ln_g  = (const float*)d_in[15];
  const float* ln_b  = (const float*)d_in[16];
  const float* W_pre = (const float*)d_in[17];
  const float* b_pre = (const float*)d_in[18];
  const float* W_out = (const float*)d_in[19];
  const float* b_out = (const float*)d_in[20];
  float* out = (float*)d_out;
  char* ws = (char*)d_ws;

  size_t off = 0;
  auto alloc = [&](size_t bytes) { void* p = ws + off; off += bytes; return p; };
  u16*   WAf  = (u16*)alloc(12582912);   // 3 planes x 2048x1024 bf16
  u16*   WBf  = (u16*)alloc(12582912);
  u16*   WPf  = (u16*)alloc(1572864);    // 3 x 512x512
  u16*   WOf  = (u16*)alloc(393216);     // 3 x 128x512
  float* GZ0  = (float*)alloc(1048576);
  float* GZ1  = (float*)alloc(1048576);
  float* gb1  = (float*)alloc(8192);
  float* zp   = (float*)alloc(262144);
  u16*   ha[2], *hbuf[2];
  ha[0]   = (u16*)alloc(393216);         // 3 planes x 128x512
  ha[1]   = (u16*)alloc(393216);
  hbuf[0] = (u16*)alloc(393216);
  hbuf[1] = (u16*)alloc(393216);
  float* ca   = (float*)alloc(262144);
  float* cb   = (float*)alloc(262144);
  u16*   sbuf = (u16*)alloc(393216);

  prep_hc0<<<512, 256, 0, stream>>>(z, W_l2h, b_l2h, W_l2c, b_l2c, ha[0], hbuf[0], ca, cb);
  prep_zp<<<256, 256, 0, stream>>>(z, W_zp, b_zp, zp);
  prep_gz<<<1024, 256, 0, stream>>>(zp, W_ih0, b_ih0, b_hh0, b_out, GZ0, GZ1);
  prep_waf<<<8192, 256, 0, stream>>>(W_out, W_ih0, W_hh0, WAf);
  prep_wbf<<<8192, 256, 0, stream>>>(W_ih1, W_hh1, WBf);
  prep_misc<<<2056, 256, 0, stream>>>(W_pre, W_out, b_ih1, b_hh1, WPf, WOf, gb1, sbuf);

  for (int t = 0; t < Ln; ++t) {
    // phase A: cell0 (128 gate blocks) + 8 ys blocks writing ys[t-1]
    cell_k<<<136, 1024, 0, stream>>>(sbuf, ha[t & 1], WAf, t ? GZ1 : GZ0, 2048,
                                     ca, ha[(t + 1) & 1], 128, sbuf, WOf, b_out, out, t);
    // phase B: cell1
    cell_k<<<128, 1024, 0, stream>>>(ha[(t + 1) & 1], hbuf[t & 1], WBf, gb1, 0,
                                     cb, hbuf[(t + 1) & 1], 128, sbuf, WOf, b_out, out, 0);
    // phase C: layernorm + pre + s'
    lnpre_k<<<256, 256, 0, stream>>>(hbuf[(t + 1) & 1], WPf, ln_g, ln_b, b_pre, sbuf);
  }
  // epilogue: ys[L-1] from final s
  cell_k<<<8, 1024, 0, stream>>>(sbuf, ha[0], WAf, GZ1, 2048, ca, ha[1],
                                 0, sbuf, WOf, b_out, out, Ln);
}